// Round 5
// baseline (356.577 us; speedup 1.0000x reference)
//
#include <hip/hip_runtime.h>
#include <math.h>

// ---------------------------------------------------------------------------
// ClustGeoNodeEncoder via two-level bucket decomposition (atomic-amortized).
//
// Global-atomic wall on MI355X measured ~16-23 G ops/s (r2/r3/r4), so the
// design amortizes allocation: bucket = cid>>8 (256 clusters per bucket).
//   p1_bucket   : per 4096-voxel round, LDS ds_add_rtn gives local ranks;
//                 256 returning global atomics per round allocate bucket
//                 space -> ~250K global atomics total (was 4M).
//   p2_features : 1 block per bucket; stream bucket twice (moments in LDS
//                 f32 atomics -> f64 eigen per cluster -> sc stream) and
//                 write all 16 outputs. No global bin, no kb.
// Fallback (small ws): round-2 packed u64 fixed-point pipeline.
// ---------------------------------------------------------------------------

// ========================= shared: 3x3 symmetric eigen =====================
__device__ inline void eig3_sym(double a00, double a01, double a02,
                                double a11, double a12, double a22,
                                double& w0, double& w1, double& w2,
                                double v[3]) {
    double p1 = a01 * a01 + a02 * a02 + a12 * a12;
    double q  = (a00 + a11 + a22) / 3.0;
    double d0 = a00 - q, d1 = a11 - q, d2 = a22 - q;
    double p2 = d0 * d0 + d1 * d1 + d2 * d2 + 2.0 * p1;
    double p  = sqrt(p2 / 6.0);
    if (p < 1e-300) {
        w0 = w1 = w2 = q;
        v[0] = 0.0; v[1] = 0.0; v[2] = 1.0;
        return;
    }
    double ip = 1.0 / p;
    double b00 = d0 * ip, b11 = d1 * ip, b22 = d2 * ip;
    double b01 = a01 * ip, b02 = a02 * ip, b12 = a12 * ip;
    double detB = b00 * (b11 * b22 - b12 * b12)
                - b01 * (b01 * b22 - b12 * b02)
                + b02 * (b01 * b12 - b11 * b02);
    double r = detB * 0.5;
    r = fmin(1.0, fmax(-1.0, r));
    double phi = acos(r) / 3.0;
    w2 = q + 2.0 * p * cos(phi);
    w0 = q + 2.0 * p * cos(phi + 2.0943951023931953);  // +2*pi/3
    w1 = 3.0 * q - w2 - w0;

    double r0x = a00 - w2, r0y = a01,       r0z = a02;
    double r1x = a01,      r1y = a11 - w2,  r1z = a12;
    double r2x = a02,      r2y = a12,       r2z = a22 - w2;

    double c0x = r0y * r1z - r0z * r1y;
    double c0y = r0z * r1x - r0x * r1z;
    double c0z = r0x * r1y - r0y * r1x;
    double n0  = c0x * c0x + c0y * c0y + c0z * c0z;

    double c1x = r0y * r2z - r0z * r2y;
    double c1y = r0z * r2x - r0x * r2z;
    double c1z = r0x * r2y - r0y * r2x;
    double n1  = c1x * c1x + c1y * c1y + c1z * c1z;

    double c2x = r1y * r2z - r1z * r2y;
    double c2y = r1z * r2x - r1x * r2z;
    double c2z = r1x * r2y - r1y * r2x;
    double n2  = c2x * c2x + c2y * c2y + c2z * c2z;

    double vx, vy, vz, nn;
    if (n0 >= n1 && n0 >= n2) { vx = c0x; vy = c0y; vz = c0z; nn = n0; }
    else if (n1 >= n2)        { vx = c1x; vy = c1y; vz = c1z; nn = n1; }
    else                      { vx = c2x; vy = c2y; vz = c2z; nn = n2; }
    if (nn < 1e-300) {
        v[0] = 0.0; v[1] = 0.0; v[2] = 1.0;
        return;
    }
    double inv = rsqrt(nn);
    v[0] = vx * inv; v[1] = vy * inv; v[2] = vz * inv;
}

// ============================ primary path =================================
#define P1_BLOCK 1024
#define P1_ITEMS 4     // voxels per thread per round -> 4096 per block-round

__global__ void p1_bucket(const float* __restrict__ data,
                          const int* __restrict__ cid,
                          unsigned int* __restrict__ gcnt,   // [256]
                          float4* __restrict__ bbuf,         // [nbuckets*cap]
                          int n_vox, int cap) {
    __shared__ unsigned int hist[256];
    __shared__ unsigned int base[256];
    const int tid = threadIdx.x;
    const int per_round = P1_BLOCK * P1_ITEMS;
    const int total_rounds = (n_vox + per_round - 1) / per_round;

    for (int r = blockIdx.x; r < total_rounds; r += gridDim.x) {
        const int start = r * per_round;
        if (tid < 256) hist[tid] = 0;
        __syncthreads();

        int   bk[P1_ITEMS];
        int   cd[P1_ITEMS];
        float px[P1_ITEMS], py[P1_ITEMS], pz[P1_ITEMS];
        unsigned int rk[P1_ITEMS];
#pragma unroll
        for (int k = 0; k < P1_ITEMS; ++k) {
            int i = start + tid + k * P1_BLOCK;   // coalesced lane pattern
            if (i < n_vox) {
                int c = cid[i];
                cd[k] = c;
                bk[k] = c >> 8;
                const float* row = data + (size_t)i * 6;
                px[k] = row[1]; py[k] = row[2]; pz[k] = row[3];
                rk[k] = atomicAdd(&hist[bk[k]], 1u);   // local rank
            } else {
                bk[k] = -1;
            }
        }
        __syncthreads();
        if (tid < 256) {
            unsigned int h = hist[tid];
            base[tid] = h ? atomicAdd(&gcnt[tid], h) : 0u;
        }
        __syncthreads();
#pragma unroll
        for (int k = 0; k < P1_ITEMS; ++k) {
            if (bk[k] >= 0) {
                unsigned int pos = base[bk[k]] + rk[k];
                if (pos < (unsigned int)cap)
                    bbuf[(size_t)bk[k] * cap + pos] =
                        make_float4(px[k], py[k], pz[k], __int_as_float(cd[k]));
            }
        }
        __syncthreads();
    }
}

#define P2_BLOCK 1024

__global__ void p2_features(const unsigned int* __restrict__ gcnt,
                            const float4* __restrict__ bbuf,
                            float* __restrict__ out,
                            int C, int cap) {
    __shared__ float mom[10][256];   // 9 moments + count, per local cluster
    __shared__ float cen[3][256];
    __shared__ float vv[3][256];
    __shared__ float scs[256];

    const int b   = blockIdx.x;
    const int tid = threadIdx.x;
    const int bcnt = min((int)gcnt[b], cap);
    const float4* src = bbuf + (size_t)b * cap;

    if (tid < 256) {
#pragma unroll
        for (int k = 0; k < 10; ++k) mom[k][tid] = 0.0f;
        scs[tid] = 0.0f;
    }
    __syncthreads();

    // ---- stream 1: moments ----
    for (int i = tid; i < bcnt; i += P2_BLOCK) {
        float4 p = src[i];
        int c = __float_as_int(p.w) & 255;
        atomicAdd(&mom[0][c], p.x);
        atomicAdd(&mom[1][c], p.y);
        atomicAdd(&mom[2][c], p.z);
        atomicAdd(&mom[3][c], p.x * p.x);
        atomicAdd(&mom[4][c], p.x * p.y);
        atomicAdd(&mom[5][c], p.x * p.z);
        atomicAdd(&mom[6][c], p.y * p.y);
        atomicAdd(&mom[7][c], p.y * p.z);
        atomicAdd(&mom[8][c], p.z * p.z);
        atomicAdd(&mom[9][c], 1.0f);
    }
    __syncthreads();

    // ---- per-cluster eigen (thread t <-> cluster (b<<8)|t) ----
    int   n = 0;
    bool  multi = false;
    float fcx = 0.f, fcy = 0.f, fcz = 0.f;
    float fvx = 0.f, fvy = 0.f, fvz = 1.f;
    float dirwt_f = 0.f;
    float b3 = 0.f, b4 = 0.f, b5 = 0.f, b7 = 0.f, b8 = 0.f, b11 = 0.f;

    if (tid < 256) {
        n = (int)mom[9][tid];
        double dn = (double)n;
        double nd = (double)max(n, 1);
        double cx = (double)mom[0][tid] / nd;
        double cy = (double)mom[1][tid] / nd;
        double cz = (double)mom[2][tid] / nd;

        double axx = (double)mom[3][tid] - dn * cx * cx;
        double axy = (double)mom[4][tid] - dn * cx * cy;
        double axz = (double)mom[5][tid] - dn * cx * cz;
        double ayy = (double)mom[6][tid] - dn * cy * cy;
        double ayz = (double)mom[7][tid] - dn * cy * cz;
        double azz = (double)mom[8][tid] - dn * cz * cz;

        double w0, w1, w2, v[3];
        eig3_sym(axx, axy, axz, ayy, ayz, azz, w0, w1, w2, v);

        double safe_w2 = (w2 > 0.0) ? w2 : 1.0;
        double isw = 1.0 / safe_w2;
        dirwt_f = (float)(1.0 - w1 / safe_w2);

        multi = (n >= 2);
        fcx = (float)cx; fcy = (float)cy; fcz = (float)cz;
        fvx = (float)v[0]; fvy = (float)v[1]; fvz = (float)v[2];
        if (multi) {
            b3  = (float)(axx * isw);
            b4  = (float)(axy * isw);
            b5  = (float)(axz * isw);
            b7  = (float)(ayy * isw);
            b8  = (float)(ayz * isw);
            b11 = (float)(azz * isw);
        }
        cen[0][tid] = fcx; cen[1][tid] = fcy; cen[2][tid] = fcz;
        vv[0][tid]  = fvx; vv[1][tid]  = fvy; vv[2][tid]  = fvz;
    }
    __syncthreads();

    // ---- stream 2: sc sign statistic (bucket data L2-hot) ----
    for (int i = tid; i < bcnt; i += P2_BLOCK) {
        float4 p = src[i];
        int c = __float_as_int(p.w) & 255;
        float x = p.x - cen[0][c];
        float y = p.y - cen[1][c];
        float z = p.z - cen[2][c];
        float wx = vv[0][c], wy = vv[1][c], wz = vv[2][c];
        float x0 = x * wx + y * wy + z * wz;
        float qx = x - x0 * wx;
        float qy = y - x0 * wy;
        float qz = z - x0 * wz;
        atomicAdd(&scs[c], x0 * sqrtf(qx * qx + qy * qy + qz * qz));
    }
    __syncthreads();

    // ---- write 16 features ----
    if (tid < 256) {
        int cl = (b << 8) | tid;
        if (cl < C) {
            float sgn = (scs[tid] < 0.0f) ? -1.0f : 1.0f;
            float m = multi ? sgn * dirwt_f : 0.0f;
            float4* o = (float4*)(out + (size_t)cl * 16);
            o[0] = make_float4(fcx, fcy, fcz, b3);
            o[1] = make_float4(b4, b5, b4, b7);
            o[2] = make_float4(b8, b5, b8, b11);
            o[3] = make_float4(fvx * m, fvy * m, fvz * m, (float)n);
        }
    }
}

// ============================ fallback path (round-2) ======================
#define FXP_SCALE 131072.0f
#define FXP_BIAS  4194304
#define FXP_INV   (1.0 / 131072.0)

__device__ __forceinline__ unsigned int fxp_enc(float v) {
    return (unsigned int)(__float2int_rn(v * FXP_SCALE) + FXP_BIAS);
}
__device__ __forceinline__ double fxp_dec(unsigned int s, int n) {
    return (double)((long long)s - (long long)n * FXP_BIAS) * FXP_INV;
}

__global__ void k1_accum(const float* __restrict__ data,
                         const int* __restrict__ cid,
                         unsigned long long* __restrict__ acc,
                         int n_vox) {
    int stride = gridDim.x * blockDim.x;
    for (int i = blockIdx.x * blockDim.x + threadIdx.x; i < n_vox; i += stride) {
        int c = cid[i];
        const float* row = data + (size_t)i * 6;
        float x = row[1], y = row[2], z = row[3];
        unsigned long long* a = acc + (size_t)c * 5;
        unsigned long long p0 = ((unsigned long long)fxp_enc(y)     << 32) | fxp_enc(x);
        unsigned long long p1 = ((unsigned long long)fxp_enc(x * x) << 32) | fxp_enc(z);
        unsigned long long p2 = ((unsigned long long)fxp_enc(x * z) << 32) | fxp_enc(x * y);
        unsigned long long p3 = ((unsigned long long)fxp_enc(y * z) << 32) | fxp_enc(y * y);
        unsigned long long p4 = (1ULL << 32)                               | fxp_enc(z * z);
        atomicAdd(&a[0], p0);
        atomicAdd(&a[1], p1);
        atomicAdd(&a[2], p2);
        atomicAdd(&a[3], p3);
        atomicAdd(&a[4], p4);
    }
}

__global__ void k2_cluster(const unsigned long long* __restrict__ acc,
                           float* __restrict__ wf,
                           float* __restrict__ out, int C) {
    int c = blockIdx.x * blockDim.x + threadIdx.x;
    if (c >= C) return;
    const unsigned long long* a = acc + (size_t)c * 5;
    unsigned long long s0 = a[0], s1 = a[1], s2 = a[2], s3 = a[3], s4 = a[4];
    int n = (int)(s4 >> 32);

    double sx  = fxp_dec((unsigned int)s0,         n);
    double sy  = fxp_dec((unsigned int)(s0 >> 32), n);
    double sz  = fxp_dec((unsigned int)s1,         n);
    double sxx = fxp_dec((unsigned int)(s1 >> 32), n);
    double sxy = fxp_dec((unsigned int)s2,         n);
    double sxz = fxp_dec((unsigned int)(s2 >> 32), n);
    double syy = fxp_dec((unsigned int)s3,         n);
    double syz = fxp_dec((unsigned int)(s3 >> 32), n);
    double szz = fxp_dec((unsigned int)s4,         n);

    double nd = (double)max(n, 1);
    double cx = sx / nd, cy = sy / nd, cz = sz / nd;
    double dn = (double)n;
    double axx = sxx - dn * cx * cx;
    double axy = sxy - dn * cx * cy;
    double axz = sxz - dn * cx * cz;
    double ayy = syy - dn * cy * cy;
    double ayz = syz - dn * cy * cz;
    double azz = szz - dn * cz * cz;

    double w0, w1, w2, v[3];
    eig3_sym(axx, axy, axz, ayy, ayz, azz, w0, w1, w2, v);

    double safe_w2 = (w2 > 0.0) ? w2 : 1.0;
    double dirwt   = 1.0 - w1 / safe_w2;
    double isw     = 1.0 / safe_w2;
    bool multi = (n >= 2);

    float* o = out + (size_t)c * 16;
    o[0] = (float)cx; o[1] = (float)cy; o[2] = (float)cz;
    if (multi) {
        o[3]  = (float)(axx * isw); o[4]  = (float)(axy * isw); o[5]  = (float)(axz * isw);
        o[6]  = (float)(axy * isw); o[7]  = (float)(ayy * isw); o[8]  = (float)(ayz * isw);
        o[9]  = (float)(axz * isw); o[10] = (float)(ayz * isw); o[11] = (float)(azz * isw);
    } else {
        o[3] = 0.f; o[4] = 0.f; o[5] = 0.f; o[6] = 0.f; o[7] = 0.f;
        o[8] = 0.f; o[9] = 0.f; o[10] = 0.f; o[11] = 0.f;
    }
    o[15] = (float)n;

    wf[(size_t)C * 1 + c] = (float)cx;
    wf[(size_t)C * 2 + c] = (float)cy;
    wf[(size_t)C * 3 + c] = (float)cz;
    wf[(size_t)C * 4 + c] = (float)v[0];
    wf[(size_t)C * 5 + c] = (float)v[1];
    wf[(size_t)C * 6 + c] = (float)v[2];
    wf[(size_t)C * 7 + c] = (float)dirwt;
}

__global__ void k3_sc(const float* __restrict__ data,
                      const int* __restrict__ cid,
                      float* __restrict__ wf,
                      int n_vox, int C) {
    const float* cenx = wf + (size_t)C * 1;
    const float* ceny = wf + (size_t)C * 2;
    const float* cenz = wf + (size_t)C * 3;
    const float* v0x  = wf + (size_t)C * 4;
    const float* v0y  = wf + (size_t)C * 5;
    const float* v0z  = wf + (size_t)C * 6;
    float* sc = wf;
    int stride = gridDim.x * blockDim.x;
    for (int i = blockIdx.x * blockDim.x + threadIdx.x; i < n_vox; i += stride) {
        int c = cid[i];
        const float* row = data + (size_t)i * 6;
        float x = row[1] - cenx[c];
        float y = row[2] - ceny[c];
        float z = row[3] - cenz[c];
        float vx = v0x[c], vy = v0y[c], vz = v0z[c];
        float x0 = x * vx + y * vy + z * vz;
        float px = x - x0 * vx;
        float py = y - x0 * vy;
        float pz = z - x0 * vz;
        atomicAdd(&sc[c], x0 * sqrtf(px * px + py * py + pz * pz));
    }
}

__global__ void k4_final(const unsigned long long* __restrict__ acc,
                         const float* __restrict__ wf,
                         float* __restrict__ out, int C) {
    int c = blockIdx.x * blockDim.x + threadIdx.x;
    if (c >= C) return;
    int n = (int)(acc[(size_t)c * 5 + 4] >> 32);
    float scv = wf[c];
    float vx  = wf[(size_t)C * 4 + c];
    float vy  = wf[(size_t)C * 5 + c];
    float vz  = wf[(size_t)C * 6 + c];
    float dir = wf[(size_t)C * 7 + c];
    float sgn = (scv < 0.0f) ? -1.0f : 1.0f;
    float m = (n >= 2) ? sgn * dir : 0.0f;
    float* o = out + (size_t)c * 16;
    o[12] = vx * m;
    o[13] = vy * m;
    o[14] = vz * m;
}

// ============================ launch =======================================
extern "C" void kernel_launch(void* const* d_in, const int* in_sizes, int n_in,
                              void* d_out, int out_size, void* d_ws, size_t ws_size,
                              hipStream_t stream) {
    const float* data = (const float*)d_in[0];
    const int*   cid  = (const int*)d_in[1];
    float* out = (float*)d_out;

    int n_vox = in_sizes[1];
    int C     = out_size / 16;

    int nbuckets = (C + 255) >> 8;
    // Per-bucket capacity: expected load (256 clusters * n_vox/C) + ~25% + pad.
    long long expected = (long long)n_vox * 256 / (C > 0 ? C : 1);
    int cap = (int)(((expected + expected / 4 + 2048) + 255) & ~255LL);
    size_t need = 1024 + (size_t)nbuckets * cap * 16;

    if (C > 0 && nbuckets <= 256 && ws_size >= need) {
        unsigned int* gcnt = (unsigned int*)d_ws;            // 256 * 4 = 1 KB
        float4* bbuf = (float4*)((char*)d_ws + 1024);
        hipMemsetAsync(d_ws, 0, 1024, stream);
        p1_bucket<<<512, P1_BLOCK, 0, stream>>>(data, cid, gcnt, bbuf, n_vox, cap);
        p2_features<<<nbuckets, P2_BLOCK, 0, stream>>>(gcnt, bbuf, out, C, cap);
    } else {
        unsigned long long* acc = (unsigned long long*)d_ws;
        float* wf = (float*)((char*)d_ws + (size_t)C * 40);
        hipMemsetAsync(d_ws, 0, (size_t)C * 44, stream);
        const int vox_blocks = 4096;
        const int cl_blocks  = (C + 255) / 256;
        k1_accum<<<vox_blocks, 256, 0, stream>>>(data, cid, acc, n_vox);
        k2_cluster<<<cl_blocks, 256, 0, stream>>>(acc, wf, out, C);
        k3_sc<<<vox_blocks, 256, 0, stream>>>(data, cid, wf, n_vox, C);
        k4_final<<<cl_blocks, 256, 0, stream>>>(acc, wf, out, C);
    }
}

// Round 6
// 171.027 us; speedup vs baseline: 2.0849x; 2.0849x over previous
//
#include <hip/hip_runtime.h>
#include <math.h>

// ---------------------------------------------------------------------------
// ClustGeoNodeEncoder via two-level bucket decomposition.
//
// Measured walls driving this design:
//   - global atomics (returning or not): ~16-23 G ops/s chip-wide (r2/r3/r4)
//   - LDS f32-atomic moment accumulation at 196-block parallelism: 301 us (r5)
// So: p1 buckets points with LDS-amortized allocation (~250K global atomics);
// p2 does an in-LDS counting sort (1+1 LDS atomics/point) and then processes
// one cluster per wave with register moments (r4 kb structure, proven fast).
//
//   p1_bucket   : bucket = cid>>8. Per 4096-voxel round: LDS ds_add_rtn local
//                 ranks, 256 returning global atomics allocate bucket space,
//                 scatter (x,y,z,cid) -> bbuf[bucket*CAP ...].
//   p2_features : 1 block (1024 thr) per bucket. LDS: hist(256) -> prefix ->
//                 idx16[CAP] cluster-sorted point indices. Then 16 waves x 16
//                 clusters: gather <=192 pts into regs, shuffle-reduce moments,
//                 redundant f64 eigen, sc from regs, write 16 feats.
// Fallback (small ws): round-2 packed u64 fixed-point pipeline.
// ---------------------------------------------------------------------------

#define CAP 24576          // per-bucket capacity (expected 20480 @ bench; +20%)

// ========================= shared: 3x3 symmetric eigen =====================
__device__ inline void eig3_sym(double a00, double a01, double a02,
                                double a11, double a12, double a22,
                                double& w0, double& w1, double& w2,
                                double v[3]) {
    double p1 = a01 * a01 + a02 * a02 + a12 * a12;
    double q  = (a00 + a11 + a22) / 3.0;
    double d0 = a00 - q, d1 = a11 - q, d2 = a22 - q;
    double p2 = d0 * d0 + d1 * d1 + d2 * d2 + 2.0 * p1;
    double p  = sqrt(p2 / 6.0);
    if (p < 1e-300) {
        w0 = w1 = w2 = q;
        v[0] = 0.0; v[1] = 0.0; v[2] = 1.0;
        return;
    }
    double ip = 1.0 / p;
    double b00 = d0 * ip, b11 = d1 * ip, b22 = d2 * ip;
    double b01 = a01 * ip, b02 = a02 * ip, b12 = a12 * ip;
    double detB = b00 * (b11 * b22 - b12 * b12)
                - b01 * (b01 * b22 - b12 * b02)
                + b02 * (b01 * b12 - b11 * b02);
    double r = detB * 0.5;
    r = fmin(1.0, fmax(-1.0, r));
    double phi = acos(r) / 3.0;
    w2 = q + 2.0 * p * cos(phi);
    w0 = q + 2.0 * p * cos(phi + 2.0943951023931953);  // +2*pi/3
    w1 = 3.0 * q - w2 - w0;

    double r0x = a00 - w2, r0y = a01,       r0z = a02;
    double r1x = a01,      r1y = a11 - w2,  r1z = a12;
    double r2x = a02,      r2y = a12,       r2z = a22 - w2;

    double c0x = r0y * r1z - r0z * r1y;
    double c0y = r0z * r1x - r0x * r1z;
    double c0z = r0x * r1y - r0y * r1x;
    double n0  = c0x * c0x + c0y * c0y + c0z * c0z;

    double c1x = r0y * r2z - r0z * r2y;
    double c1y = r0z * r2x - r0x * r2z;
    double c1z = r0x * r2y - r0y * r2x;
    double n1  = c1x * c1x + c1y * c1y + c1z * c1z;

    double c2x = r1y * r2z - r1z * r2y;
    double c2y = r1z * r2x - r1x * r2z;
    double c2z = r1x * r2y - r1y * r2x;
    double n2  = c2x * c2x + c2y * c2y + c2z * c2z;

    double vx, vy, vz, nn;
    if (n0 >= n1 && n0 >= n2) { vx = c0x; vy = c0y; vz = c0z; nn = n0; }
    else if (n1 >= n2)        { vx = c1x; vy = c1y; vz = c1z; nn = n1; }
    else                      { vx = c2x; vy = c2y; vz = c2z; nn = n2; }
    if (nn < 1e-300) {
        v[0] = 0.0; v[1] = 0.0; v[2] = 1.0;
        return;
    }
    double inv = rsqrt(nn);
    v[0] = vx * inv; v[1] = vy * inv; v[2] = vz * inv;
}

// ============================ primary path =================================
#define P1_BLOCK 1024
#define P1_ITEMS 4     // voxels per thread per round -> 4096 per block-round

__global__ void p1_bucket(const float* __restrict__ data,
                          const int* __restrict__ cid,
                          unsigned int* __restrict__ gcnt,   // [256]
                          float4* __restrict__ bbuf,         // [nbuckets*CAP]
                          int n_vox) {
    __shared__ unsigned int hist[256];
    __shared__ unsigned int base[256];
    const int tid = threadIdx.x;
    const int per_round = P1_BLOCK * P1_ITEMS;
    const int total_rounds = (n_vox + per_round - 1) / per_round;

    for (int r = blockIdx.x; r < total_rounds; r += gridDim.x) {
        const int start = r * per_round;
        if (tid < 256) hist[tid] = 0;
        __syncthreads();

        int   bk[P1_ITEMS];
        int   cd[P1_ITEMS];
        float px[P1_ITEMS], py[P1_ITEMS], pz[P1_ITEMS];
        unsigned int rk[P1_ITEMS];
#pragma unroll
        for (int k = 0; k < P1_ITEMS; ++k) {
            int i = start + tid + k * P1_BLOCK;   // coalesced lane pattern
            if (i < n_vox) {
                int c = cid[i];
                cd[k] = c;
                bk[k] = c >> 8;
                const float* row = data + (size_t)i * 6;
                px[k] = row[1]; py[k] = row[2]; pz[k] = row[3];
                rk[k] = atomicAdd(&hist[bk[k]], 1u);   // local rank
            } else {
                bk[k] = -1;
            }
        }
        __syncthreads();
        if (tid < 256) {
            unsigned int h = hist[tid];
            base[tid] = h ? atomicAdd(&gcnt[tid], h) : 0u;
        }
        __syncthreads();
#pragma unroll
        for (int k = 0; k < P1_ITEMS; ++k) {
            if (bk[k] >= 0) {
                unsigned int pos = base[bk[k]] + rk[k];
                if (pos < (unsigned int)CAP)
                    bbuf[(size_t)bk[k] * CAP + pos] =
                        make_float4(px[k], py[k], pz[k], __int_as_float(cd[k]));
            }
        }
        __syncthreads();
    }
}

__global__ __launch_bounds__(1024) void p2_features(
        const unsigned int* __restrict__ gcnt,
        const float4* __restrict__ bbuf,
        float* __restrict__ out,
        int C) {
    __shared__ unsigned int hist[256];    // per-cluster counts
    __shared__ unsigned int base[256];    // exclusive starts
    __shared__ unsigned int hist2[256];   // pass-2 rank counters
    __shared__ unsigned short idx16[CAP]; // cluster-sorted point indices

    const int b   = blockIdx.x;
    const int tid = threadIdx.x;
    const int bcnt = min((int)gcnt[b], CAP);
    const float4* src = bbuf + (size_t)b * CAP;

    if (tid < 256) { hist[tid] = 0; hist2[tid] = 0; }
    __syncthreads();

    // pass 1: per-cluster histogram (1 LDS atomic / point)
    for (int i = tid; i < bcnt; i += 1024) {
        int c = __float_as_int(src[i].w) & 255;
        atomicAdd(&hist[c], 1u);
    }
    __syncthreads();

    // inclusive scan (Hillis-Steele) then convert to exclusive
    if (tid < 256) base[tid] = hist[tid];
    __syncthreads();
    for (int off = 1; off < 256; off <<= 1) {
        unsigned int v = 0;
        if (tid < 256 && tid >= off) v = base[tid - off];
        __syncthreads();
        if (tid < 256) base[tid] += v;
        __syncthreads();
    }
    if (tid < 256) base[tid] -= hist[tid];
    __syncthreads();

    // pass 2: counting-sort indices into idx16
    for (int i = tid; i < bcnt; i += 1024) {
        int c = __float_as_int(src[i].w) & 255;
        unsigned int rk = atomicAdd(&hist2[c], 1u);
        idx16[base[c] + rk] = (unsigned short)i;
    }
    __syncthreads();

    // wave-per-cluster processing: wave w handles clusters w*16 .. w*16+15
    const int w    = tid >> 6;
    const int lane = tid & 63;

    for (int jj = 0; jj < 16; ++jj) {
        int t  = (w << 4) | jj;
        int cl = (b << 8) | t;
        if (cl >= C) continue;          // uniform per wave
        int n = (int)hist[t];
        unsigned int nb = base[t];

        float4 q0 = make_float4(0.f, 0.f, 0.f, 0.f), q1 = q0, q2 = q0;
        bool m0 = lane < n, m1 = lane + 64 < n, m2 = lane + 128 < n;
        if (m0) q0 = src[idx16[nb + lane]];
        if (m1) q1 = src[idx16[nb + lane + 64]];
        if (m2) q2 = src[idx16[nb + lane + 128]];

        float s[9];
        s[0] = q0.x + q1.x + q2.x;
        s[1] = q0.y + q1.y + q2.y;
        s[2] = q0.z + q1.z + q2.z;
        s[3] = q0.x * q0.x + q1.x * q1.x + q2.x * q2.x;
        s[4] = q0.x * q0.y + q1.x * q1.y + q2.x * q2.y;
        s[5] = q0.x * q0.z + q1.x * q1.z + q2.x * q2.z;
        s[6] = q0.y * q0.y + q1.y * q1.y + q2.y * q2.y;
        s[7] = q0.y * q0.z + q1.y * q1.z + q2.y * q2.z;
        s[8] = q0.z * q0.z + q1.z * q1.z + q2.z * q2.z;

        // rare big-cluster path (n > 192)
        for (int j = lane + 192; j < n; j += 64) {
            float4 p = src[idx16[nb + j]];
            s[0] += p.x;       s[1] += p.y;       s[2] += p.z;
            s[3] += p.x * p.x; s[4] += p.x * p.y; s[5] += p.x * p.z;
            s[6] += p.y * p.y; s[7] += p.y * p.z; s[8] += p.z * p.z;
        }
#pragma unroll
        for (int d = 32; d > 0; d >>= 1) {
#pragma unroll
            for (int k = 0; k < 9; ++k) s[k] += __shfl_xor(s[k], d);
        }

        // all lanes hold full sums; redundant f64 eigen (no divergence)
        double dn = (double)n;
        double nd = (double)max(n, 1);
        double cx = (double)s[0] / nd, cy = (double)s[1] / nd, cz = (double)s[2] / nd;

        double axx = (double)s[3] - dn * cx * cx;
        double axy = (double)s[4] - dn * cx * cy;
        double axz = (double)s[5] - dn * cx * cz;
        double ayy = (double)s[6] - dn * cy * cy;
        double ayz = (double)s[7] - dn * cy * cz;
        double azz = (double)s[8] - dn * cz * cz;

        double w0, w1, w2, v[3];
        eig3_sym(axx, axy, axz, ayy, ayz, azz, w0, w1, w2, v);

        double safe_w2 = (w2 > 0.0) ? w2 : 1.0;
        double dirwt   = 1.0 - w1 / safe_w2;
        double isw     = 1.0 / safe_w2;

        float fcx = (float)cx, fcy = (float)cy, fcz = (float)cz;
        float vx = (float)v[0], vy = (float)v[1], vz = (float)v[2];
        float sc = 0.0f;
        if (m0) {
            float x = q0.x - fcx, y = q0.y - fcy, z = q0.z - fcz;
            float x0 = x * vx + y * vy + z * vz;
            float qx = x - x0 * vx, qy = y - x0 * vy, qz = z - x0 * vz;
            sc += x0 * sqrtf(qx * qx + qy * qy + qz * qz);
        }
        if (m1) {
            float x = q1.x - fcx, y = q1.y - fcy, z = q1.z - fcz;
            float x0 = x * vx + y * vy + z * vz;
            float qx = x - x0 * vx, qy = y - x0 * vy, qz = z - x0 * vz;
            sc += x0 * sqrtf(qx * qx + qy * qy + qz * qz);
        }
        if (m2) {
            float x = q2.x - fcx, y = q2.y - fcy, z = q2.z - fcz;
            float x0 = x * vx + y * vy + z * vz;
            float qx = x - x0 * vx, qy = y - x0 * vy, qz = z - x0 * vz;
            sc += x0 * sqrtf(qx * qx + qy * qy + qz * qz);
        }
        for (int j = lane + 192; j < n; j += 64) {
            float4 p = src[idx16[nb + j]];
            float x = p.x - fcx, y = p.y - fcy, z = p.z - fcz;
            float x0 = x * vx + y * vy + z * vz;
            float qx = x - x0 * vx, qy = y - x0 * vy, qz = z - x0 * vz;
            sc += x0 * sqrtf(qx * qx + qy * qy + qz * qz);
        }
#pragma unroll
        for (int d = 32; d > 0; d >>= 1) sc += __shfl_xor(sc, d);

        if (lane == 0) {
            bool multi = (n >= 2);
            float sgn = (sc < 0.0f) ? -1.0f : 1.0f;
            float m = multi ? sgn * (float)dirwt : 0.0f;
            float b3  = multi ? (float)(axx * isw) : 0.0f;
            float b4  = multi ? (float)(axy * isw) : 0.0f;
            float b5  = multi ? (float)(axz * isw) : 0.0f;
            float b7  = multi ? (float)(ayy * isw) : 0.0f;
            float b8  = multi ? (float)(ayz * isw) : 0.0f;
            float b11 = multi ? (float)(azz * isw) : 0.0f;
            float4* o = (float4*)(out + (size_t)cl * 16);
            o[0] = make_float4(fcx, fcy, fcz, b3);
            o[1] = make_float4(b4, b5, b4, b7);
            o[2] = make_float4(b8, b5, b8, b11);
            o[3] = make_float4(vx * m, vy * m, vz * m, (float)n);
        }
    }
}

// ============================ fallback path (round-2) ======================
#define FXP_SCALE 131072.0f
#define FXP_BIAS  4194304
#define FXP_INV   (1.0 / 131072.0)

__device__ __forceinline__ unsigned int fxp_enc(float v) {
    return (unsigned int)(__float2int_rn(v * FXP_SCALE) + FXP_BIAS);
}
__device__ __forceinline__ double fxp_dec(unsigned int s, int n) {
    return (double)((long long)s - (long long)n * FXP_BIAS) * FXP_INV;
}

__global__ void k1_accum(const float* __restrict__ data,
                         const int* __restrict__ cid,
                         unsigned long long* __restrict__ acc,
                         int n_vox) {
    int stride = gridDim.x * blockDim.x;
    for (int i = blockIdx.x * blockDim.x + threadIdx.x; i < n_vox; i += stride) {
        int c = cid[i];
        const float* row = data + (size_t)i * 6;
        float x = row[1], y = row[2], z = row[3];
        unsigned long long* a = acc + (size_t)c * 5;
        unsigned long long p0 = ((unsigned long long)fxp_enc(y)     << 32) | fxp_enc(x);
        unsigned long long p1 = ((unsigned long long)fxp_enc(x * x) << 32) | fxp_enc(z);
        unsigned long long p2 = ((unsigned long long)fxp_enc(x * z) << 32) | fxp_enc(x * y);
        unsigned long long p3 = ((unsigned long long)fxp_enc(y * z) << 32) | fxp_enc(y * y);
        unsigned long long p4 = (1ULL << 32)                               | fxp_enc(z * z);
        atomicAdd(&a[0], p0);
        atomicAdd(&a[1], p1);
        atomicAdd(&a[2], p2);
        atomicAdd(&a[3], p3);
        atomicAdd(&a[4], p4);
    }
}

__global__ void k2_cluster(const unsigned long long* __restrict__ acc,
                           float* __restrict__ wf,
                           float* __restrict__ out, int C) {
    int c = blockIdx.x * blockDim.x + threadIdx.x;
    if (c >= C) return;
    const unsigned long long* a = acc + (size_t)c * 5;
    unsigned long long s0 = a[0], s1 = a[1], s2 = a[2], s3 = a[3], s4 = a[4];
    int n = (int)(s4 >> 32);

    double sx  = fxp_dec((unsigned int)s0,         n);
    double sy  = fxp_dec((unsigned int)(s0 >> 32), n);
    double sz  = fxp_dec((unsigned int)s1,         n);
    double sxx = fxp_dec((unsigned int)(s1 >> 32), n);
    double sxy = fxp_dec((unsigned int)s2,         n);
    double sxz = fxp_dec((unsigned int)(s2 >> 32), n);
    double syy = fxp_dec((unsigned int)s3,         n);
    double syz = fxp_dec((unsigned int)(s3 >> 32), n);
    double szz = fxp_dec((unsigned int)s4,         n);

    double nd = (double)max(n, 1);
    double cx = sx / nd, cy = sy / nd, cz = sz / nd;
    double dn = (double)n;
    double axx = sxx - dn * cx * cx;
    double axy = sxy - dn * cx * cy;
    double axz = sxz - dn * cx * cz;
    double ayy = syy - dn * cy * cy;
    double ayz = syz - dn * cy * cz;
    double azz = szz - dn * cz * cz;

    double w0, w1, w2, v[3];
    eig3_sym(axx, axy, axz, ayy, ayz, azz, w0, w1, w2, v);

    double safe_w2 = (w2 > 0.0) ? w2 : 1.0;
    double dirwt   = 1.0 - w1 / safe_w2;
    double isw     = 1.0 / safe_w2;
    bool multi = (n >= 2);

    float* o = out + (size_t)c * 16;
    o[0] = (float)cx; o[1] = (float)cy; o[2] = (float)cz;
    if (multi) {
        o[3]  = (float)(axx * isw); o[4]  = (float)(axy * isw); o[5]  = (float)(axz * isw);
        o[6]  = (float)(axy * isw); o[7]  = (float)(ayy * isw); o[8]  = (float)(ayz * isw);
        o[9]  = (float)(axz * isw); o[10] = (float)(ayz * isw); o[11] = (float)(azz * isw);
    } else {
        o[3] = 0.f; o[4] = 0.f; o[5] = 0.f; o[6] = 0.f; o[7] = 0.f;
        o[8] = 0.f; o[9] = 0.f; o[10] = 0.f; o[11] = 0.f;
    }
    o[15] = (float)n;

    wf[(size_t)C * 1 + c] = (float)cx;
    wf[(size_t)C * 2 + c] = (float)cy;
    wf[(size_t)C * 3 + c] = (float)cz;
    wf[(size_t)C * 4 + c] = (float)v[0];
    wf[(size_t)C * 5 + c] = (float)v[1];
    wf[(size_t)C * 6 + c] = (float)v[2];
    wf[(size_t)C * 7 + c] = (float)dirwt;
}

__global__ void k3_sc(const float* __restrict__ data,
                      const int* __restrict__ cid,
                      float* __restrict__ wf,
                      int n_vox, int C) {
    const float* cenx = wf + (size_t)C * 1;
    const float* ceny = wf + (size_t)C * 2;
    const float* cenz = wf + (size_t)C * 3;
    const float* v0x  = wf + (size_t)C * 4;
    const float* v0y  = wf + (size_t)C * 5;
    const float* v0z  = wf + (size_t)C * 6;
    float* sc = wf;
    int stride = gridDim.x * blockDim.x;
    for (int i = blockIdx.x * blockDim.x + threadIdx.x; i < n_vox; i += stride) {
        int c = cid[i];
        const float* row = data + (size_t)i * 6;
        float x = row[1] - cenx[c];
        float y = row[2] - ceny[c];
        float z = row[3] - cenz[c];
        float vx = v0x[c], vy = v0y[c], vz = v0z[c];
        float x0 = x * vx + y * vy + z * vz;
        float px = x - x0 * vx;
        float py = y - x0 * vy;
        float pz = z - x0 * vz;
        atomicAdd(&sc[c], x0 * sqrtf(px * px + py * py + pz * pz));
    }
}

__global__ void k4_final(const unsigned long long* __restrict__ acc,
                         const float* __restrict__ wf,
                         float* __restrict__ out, int C) {
    int c = blockIdx.x * blockDim.x + threadIdx.x;
    if (c >= C) return;
    int n = (int)(acc[(size_t)c * 5 + 4] >> 32);
    float scv = wf[c];
    float vx  = wf[(size_t)C * 4 + c];
    float vy  = wf[(size_t)C * 5 + c];
    float vz  = wf[(size_t)C * 6 + c];
    float dir = wf[(size_t)C * 7 + c];
    float sgn = (scv < 0.0f) ? -1.0f : 1.0f;
    float m = (n >= 2) ? sgn * dir : 0.0f;
    float* o = out + (size_t)c * 16;
    o[12] = vx * m;
    o[13] = vy * m;
    o[14] = vz * m;
}

// ============================ launch =======================================
extern "C" void kernel_launch(void* const* d_in, const int* in_sizes, int n_in,
                              void* d_out, int out_size, void* d_ws, size_t ws_size,
                              hipStream_t stream) {
    const float* data = (const float*)d_in[0];
    const int*   cid  = (const int*)d_in[1];
    float* out = (float*)d_out;

    int n_vox = in_sizes[1];
    int C     = out_size / 16;

    int nbuckets = (C + 255) >> 8;
    long long expected = (C > 0) ? (long long)n_vox * 256 / C : 0;
    size_t need = 1024 + (size_t)nbuckets * CAP * 16;

    // primary path requires: buckets fit 256-counter LDS scheme, expected
    // bucket load comfortably below CAP, and ws big enough.
    if (C > 0 && nbuckets <= 256 && expected <= (CAP * 7) / 8 && ws_size >= need) {
        unsigned int* gcnt = (unsigned int*)d_ws;            // 256 * 4 = 1 KB
        float4* bbuf = (float4*)((char*)d_ws + 1024);
        hipMemsetAsync(d_ws, 0, 1024, stream);
        p1_bucket<<<512, P1_BLOCK, 0, stream>>>(data, cid, gcnt, bbuf, n_vox);
        p2_features<<<nbuckets, 1024, 0, stream>>>(gcnt, bbuf, out, C);
    } else {
        unsigned long long* acc = (unsigned long long*)d_ws;
        float* wf = (float*)((char*)d_ws + (size_t)C * 40);
        hipMemsetAsync(d_ws, 0, (size_t)C * 44, stream);
        const int vox_blocks = 4096;
        const int cl_blocks  = (C + 255) / 256;
        k1_accum<<<vox_blocks, 256, 0, stream>>>(data, cid, acc, n_vox);
        k2_cluster<<<cl_blocks, 256, 0, stream>>>(acc, wf, out, C);
        k3_sc<<<vox_blocks, 256, 0, stream>>>(data, cid, wf, n_vox, C);
        k4_final<<<cl_blocks, 256, 0, stream>>>(acc, wf, out, C);
    }
}